// Round 1
// baseline (1130.844 us; speedup 1.0000x reference)
//
#include <hip/hip_runtime.h>
#include <cmath>

#define D 64
#define BLK 256
#define PPT 2          // points per thread in assign kernel
#define KC 256         // k-chunk staged in LDS (== BLK)
#define MARGIN 1e-2f   // fp32 top-2 gap below this -> fp64 refine (fp32 err bound ~2.5e-4)

// ---------------- K0: wn[k] = 0.5*||w_k||^2 (fp32) ----------------
__global__ void k_wn(const float* __restrict__ w, float* __restrict__ wn, int K) {
    int k = blockIdx.x * blockDim.x + threadIdx.x;
    if (k >= K) return;
    float s = 0.f;
    for (int d = 0; d < D; ++d) {
        float v = w[(size_t)d * K + k];
        s = fmaf(v, v, s);
    }
    wn[k] = 0.5f * s;
}

// ---------------- K2: fp32 argmax of t_k = x.w_k - wn_k, top-2 margin flag ----------------
__global__ __launch_bounds__(BLK, 2) void k_assign(
    const float* __restrict__ x, const float* __restrict__ w,
    const float* __restrict__ wn, unsigned int* __restrict__ idx_out,
    float* __restrict__ quant, int N, int K)
{
    __shared__ float lds_w[KC][D + 4];   // +4 pad: 16B-aligned rows, breaks write conflicts a bit
    __shared__ float lds_wn[KC];
    const int tid = threadIdx.x;
    const long long nbase = (long long)blockIdx.x * (BLK * PPT);

    // load x rows for the 2 points into registers (32 float4 = 128 VGPRs)
    float4 xa[PPT][D / 4];
    for (int p = 0; p < PPT; ++p) {
        long long n = nbase + p * BLK + tid;
        if (n >= N) n = N - 1;           // N divisible in practice; safe clamp
        const float4* xr = (const float4*)(x + n * D);
        #pragma unroll
        for (int i = 0; i < D / 4; ++i) xa[p][i] = xr[i];
    }

    float best0 = -INFINITY, best1 = -INFINITY;
    float sec0 = -INFINITY, sec1 = -INFINITY;
    int bi0 = 0, bi1 = 0;

    for (int k0 = 0; k0 < K; k0 += KC) {
        __syncthreads();
        // stage chunk: thread tid owns code (k0+tid); coalesced 1KB global reads per d
        #pragma unroll 8
        for (int d = 0; d < D; ++d)
            lds_w[tid][d] = w[(size_t)d * K + (k0 + tid)];
        lds_wn[tid] = wn[k0 + tid];
        __syncthreads();

        for (int kc = 0; kc < KC; ++kc) {
            const float4* wr = (const float4*)(&lds_w[kc][0]);  // broadcast reads
            const float wnk = lds_wn[kc];
            float dot0 = -wnk, dot1 = -wnk;
            #pragma unroll
            for (int i = 0; i < D / 4; ++i) {
                float4 wv = wr[i];
                dot0 = fmaf(xa[0][i].x, wv.x, dot0);
                dot0 = fmaf(xa[0][i].y, wv.y, dot0);
                dot0 = fmaf(xa[0][i].z, wv.z, dot0);
                dot0 = fmaf(xa[0][i].w, wv.w, dot0);
                dot1 = fmaf(xa[1][i].x, wv.x, dot1);
                dot1 = fmaf(xa[1][i].y, wv.y, dot1);
                dot1 = fmaf(xa[1][i].z, wv.z, dot1);
                dot1 = fmaf(xa[1][i].w, wv.w, dot1);
            }
            const int kk = k0 + kc;
            {   // strict > keeps smallest k on exact ties (matches argmax first-occurrence)
                bool g = dot0 > best0;
                sec0  = g ? best0 : fmaxf(sec0, dot0);
                best0 = g ? dot0 : best0;
                bi0   = g ? kk : bi0;
            }
            {
                bool g = dot1 > best1;
                sec1  = g ? best1 : fmaxf(sec1, dot1);
                best1 = g ? dot1 : best1;
                bi1   = g ? kk : bi1;
            }
        }
    }

    const float bests[PPT] = {best0, best1};
    const float secs[PPT]  = {sec0, sec1};
    const int   bis[PPT]   = {bi0, bi1};
    for (int p = 0; p < PPT; ++p) {
        long long n = nbase + p * BLK + tid;
        if (n >= N) continue;
        unsigned flag = ((bests[p] - secs[p]) < MARGIN) ? 0x80000000u : 0u;
        idx_out[n] = (unsigned)bis[p] | flag;
        const float* wc = w + bis[p];
        float4* qd = (float4*)(quant + n * D);
        #pragma unroll
        for (int i = 0; i < D / 4; ++i) {
            float4 q;
            q.x = wc[(size_t)(4 * i + 0) * K];
            q.y = wc[(size_t)(4 * i + 1) * K];
            q.z = wc[(size_t)(4 * i + 2) * K];
            q.w = wc[(size_t)(4 * i + 3) * K];
            qd[i] = q;
        }
    }
}

// ---------------- K3: fp64 exact rescan of flagged points (rare) ----------------
__global__ void k_refine(const float* __restrict__ x, const float* __restrict__ w,
                         unsigned int* __restrict__ idx_io, float* __restrict__ quant,
                         int N, int K)
{
    const int gtid = blockIdx.x * blockDim.x + threadIdx.x;
    const int lane = threadIdx.x & 63;
    const long long wave = gtid >> 6;
    const long long nwaves = (long long)(gridDim.x * blockDim.x) >> 6;

    for (long long base = wave * 64; base < N; base += nwaves * 64) {
        long long n = base + lane;
        unsigned v = (n < (long long)N) ? idx_io[n] : 0u;
        unsigned long long flags = __ballot(v >> 31);
        while (flags) {
            int j = __ffsll(flags) - 1;
            flags &= flags - 1;
            long long p = base + j;
            // all lanes read the same x row (L1 broadcast)
            float xr[D];
            #pragma unroll 8
            for (int d = 0; d < D; ++d) xr[d] = x[p * D + d];
            double bt = -1e300;
            int bk = 0;
            for (int k = lane; k < K; k += 64) {   // ascending k per lane; strict > = first-occurrence
                double t = 0.0, s = 0.0;
                #pragma unroll 8
                for (int d = 0; d < D; ++d) {
                    double wd = (double)w[(size_t)d * K + k];
                    t = fma((double)xr[d], wd, t);
                    s = fma(wd, wd, s);
                }
                t -= 0.5 * s;
                if (t > bt) { bt = t; bk = k; }
            }
            #pragma unroll
            for (int off = 32; off > 0; off >>= 1) {
                double ot = __shfl_down(bt, off);
                int    ok = __shfl_down(bk, off);
                if (ot > bt || (ot == bt && ok < bk)) { bt = ot; bk = ok; }
            }
            int fk = __shfl(bk, 0);
            if (lane == 0) idx_io[p] = (unsigned)fk;     // clear flag
            quant[p * D + lane] = w[(size_t)lane * K + fk];
        }
    }
}

// ---------------- K4: scatter x into [K][D] partial sums + counts ----------------
__global__ void k_scatter(const float* __restrict__ x, const unsigned int* __restrict__ idx,
                          float* __restrict__ cs, float* __restrict__ cn, int N)
{
    const int gtid = blockIdx.x * blockDim.x + threadIdx.x;
    const int lane = threadIdx.x & 63;
    const long long wave = gtid >> 6;
    const long long nwaves = (long long)(gridDim.x * blockDim.x) >> 6;
    for (long long p = wave; p < N; p += nwaves) {
        unsigned k = idx[p] & 0x7fffffffu;
        float v = x[p * D + lane];
        unsafeAtomicAdd(&cs[(size_t)k * D + lane], v);   // coalesced 256B burst per wave
        if (lane == 0) unsafeAtomicAdd(&cn[k], 1.0f);
    }
}

// ---------------- K5: EMA combine -> new_w [D][K] ----------------
__global__ void k_combine(const float* __restrict__ c_sum, const float* __restrict__ c_n,
                          const float* __restrict__ cs, const float* __restrict__ cn,
                          float* __restrict__ outw, int K)
{
    int i = blockIdx.x * blockDim.x + threadIdx.x;   // i = d*K + k
    if (i >= D * K) return;
    int k = i % K;
    int d = i / K;
    const float g  = 0.99f;
    const float og = (float)(1.0 - 0.99);            // match python 1.0-GAMMA rounding
    float ns = c_sum[i] * g + cs[(size_t)k * D + d] * og;
    float nn = c_n[k] * g + cn[k] * og;
    outw[i] = ns / nn;
}

extern "C" void kernel_launch(void* const* d_in, const int* in_sizes, int n_in,
                              void* d_out, int out_size, void* d_ws, size_t ws_size,
                              hipStream_t stream)
{
    const float* x     = (const float*)d_in[0];
    const float* w     = (const float*)d_in[1];
    const float* c_sum = (const float*)d_in[2];
    const float* c_n   = (const float*)d_in[3];
    const int N = in_sizes[0] / D;
    const int K = in_sizes[3];

    float* quant = (float*)d_out;                      // N*D
    float* outw  = (float*)d_out + (size_t)N * D;      // D*K

    char* ws = (char*)d_ws;
    unsigned* idx = (unsigned*)ws;                                     // N ints
    float* cs = (float*)(ws + (size_t)N * 4);                          // K*D ([K][D])
    float* cn = (float*)(ws + (size_t)N * 4 + (size_t)K * D * 4);      // K
    float* wn = cn + K;                                                // K

    hipMemsetAsync(cs, 0, (size_t)(K * D + K) * sizeof(float), stream);
    k_wn<<<(K + 255) / 256, 256, 0, stream>>>(w, wn, K);

    int grid_assign = (N + BLK * PPT - 1) / (BLK * PPT);               // 512 blocks
    k_assign<<<grid_assign, BLK, 0, stream>>>(x, w, wn, idx, quant, N, K);

    k_refine<<<256, 256, 0, stream>>>(x, w, idx, quant, N, K);
    k_scatter<<<512, 256, 0, stream>>>(x, idx, cs, cn, N);
    k_combine<<<(D * K + 255) / 256, 256, 0, stream>>>(c_sum, c_n, cs, cn, outw, K);
}